// Round 1
// baseline (225.002 us; speedup 1.0000x reference)
//
#include <hip/hip_runtime.h>

// Problem constants (B=4, S=2048 -> T=8192 tokens; H=1024; E=8 experts)
constexpr int kT = 8192;
constexpr int kH = 1024;
constexpr int kE = 8;
constexpr int kMaxRows  = 9216;   // kT + kE*128 (per-expert 128-padding worst case)
constexpr int kMaxTiles = 72;     // kT/128 + kE

typedef short short8 __attribute__((ext_vector_type(8)));
typedef float floatx4 __attribute__((ext_vector_type(4)));

__device__ inline unsigned short f2b(float f) {
    union { float f; unsigned int u; } v; v.f = f;
    unsigned int r = v.u + 0x7FFFu + ((v.u >> 16) & 1u);  // round-to-nearest-even
    return (unsigned short)(r >> 16);
}

// ---------------- K0: zero expert counts ----------------
__global__ void k_zero_cnt(int* __restrict__ cnt) {
    if (threadIdx.x < kE) cnt[threadIdx.x] = 0;
}

// ---------------- K1: transpose+convert expert_w [E][k][n] f32 -> Wt [E][n][k] bf16 ----------------
__global__ __launch_bounds__(256) void k_transpose_w(const float* __restrict__ W,
                                                     unsigned short* __restrict__ Wt) {
    __shared__ float lds[64][65];   // odd stride: conflict-free scalar access both phases
    int kb = blockIdx.x, nb = blockIdx.y, e = blockIdx.z;
    int tid = threadIdx.x;
    int rr = tid >> 4, c4 = tid & 15;
    const float* Wp = W + ((size_t)e << 20) + (size_t)(kb * 64) * kH + nb * 64;
#pragma unroll
    for (int p = 0; p < 4; ++p) {
        int r = p * 16 + rr;  // local k
        float4 v = *(const float4*)(Wp + (size_t)r * kH + c4 * 4);
        lds[r][c4 * 4 + 0] = v.x; lds[r][c4 * 4 + 1] = v.y;
        lds[r][c4 * 4 + 2] = v.z; lds[r][c4 * 4 + 3] = v.w;
    }
    __syncthreads();
    unsigned short* Wo = Wt + ((size_t)e << 20) + (size_t)(nb * 64) * kH + kb * 64;
#pragma unroll
    for (int p = 0; p < 4; ++p) {
        int n = p * 16 + rr;  // local n
        ushort4 o;
        o.x = f2b(lds[c4 * 4 + 0][n]);
        o.y = f2b(lds[c4 * 4 + 1][n]);
        o.z = f2b(lds[c4 * 4 + 2][n]);
        o.w = f2b(lds[c4 * 4 + 3][n]);
        *(ushort4*)(Wo + (size_t)n * kH + c4 * 4) = o;
    }
}

// ---------------- K2: router (logits -> softmax -> argmax -> gate, rank via atomic) ----------------
// One wave = 8 tokens x 8 experts (lane = tg*8 + e).
__global__ __launch_bounds__(256) void k_router(const float* __restrict__ x,
                                                const float* __restrict__ rw,
                                                const float* __restrict__ rb,
                                                int* __restrict__ idx, float* __restrict__ gate,
                                                int* __restrict__ rank, int* __restrict__ cnt) {
    int gtid = blockIdx.x * 256 + threadIdx.x;
    int wave = gtid >> 6;
    int lane = gtid & 63;
    int tg = lane >> 3, e = lane & 7;
    int t = wave * 8 + tg;
    const float* xp = x + (size_t)t * kH;
    float acc = rb[e];
    for (int h4 = 0; h4 < kH / 4; ++h4) {
        float4 xv = *(const float4*)(xp + h4 * 4);
        acc += xv.x * rw[(h4 * 4 + 0) * kE + e];
        acc += xv.y * rw[(h4 * 4 + 1) * kE + e];
        acc += xv.z * rw[(h4 * 4 + 2) * kE + e];
        acc += xv.w * rw[(h4 * 4 + 3) * kE + e];
    }
    // argmax over the 8 expert lanes (first-max tie-break like np.argmax)
    float m = acc; int bi = e;
#pragma unroll
    for (int s = 1; s < 8; s <<= 1) {
        float om = __shfl_xor(m, s);
        int   ob = __shfl_xor(bi, s);
        if (om > m || (om == m && ob < bi)) { m = om; bi = ob; }
    }
    float p = __expf(acc - m);
    float sum = p;
#pragma unroll
    for (int s = 1; s < 8; s <<= 1) sum += __shfl_xor(sum, s);
    if (e == 0) {
        idx[t]  = bi;
        gate[t] = 1.0f / sum;           // softmax prob at argmax
        rank[t] = atomicAdd(&cnt[bi], 1);
    }
}

// ---------------- K3: scan counts -> 128-aligned segment offsets + m-tile table ----------------
__global__ void k_scan(const int* __restrict__ cnt, int* __restrict__ aoff,
                       int* __restrict__ tile_e, int* __restrict__ tile_row) {
    if (threadIdx.x != 0) return;
    int off = 0, tt = 0;
    for (int e = 0; e < kE; ++e) {
        aoff[e] = off;
        int c = cnt[e];
        int nt = (c + 127) >> 7;
        for (int i = 0; i < nt; ++i) { tile_e[tt] = e; tile_row[tt] = off + (i << 7); ++tt; }
        off += nt << 7;
    }
    aoff[kE] = off;
    for (; tt < kMaxTiles; ++tt) tile_e[tt] = -1;
}

// ---------------- K4: build permutation (sorted row -> token) ----------------
__global__ __launch_bounds__(256) void k_perm(const int* __restrict__ idx,
                                              const int* __restrict__ rank,
                                              const int* __restrict__ aoff,
                                              int* __restrict__ perm) {
    int t = blockIdx.x * 256 + threadIdx.x;
    perm[aoff[idx[t]] + rank[t]] = t;
}

// ---------------- K5: gather tokens into sorted bf16 A; zero pad rows ----------------
__global__ __launch_bounds__(256) void k_gather(const float* __restrict__ x,
                                                const int* __restrict__ aoff,
                                                const int* __restrict__ cnt,
                                                int* __restrict__ perm,
                                                unsigned short* __restrict__ A) {
    int r = blockIdx.x;
    if (r >= aoff[kE]) return;
    int e = 0;
    while (r >= aoff[e + 1]) ++e;     // block-uniform, <=8 iters
    int local = r - aoff[e];
    int c = threadIdx.x;
    unsigned short* Ar = A + (size_t)r * kH;
    if (local < cnt[e]) {
        int tok = perm[r];
        const float* xp = x + (size_t)tok * kH;
        float4 v = *(const float4*)(xp + c * 4);
        ushort4 o; o.x = f2b(v.x); o.y = f2b(v.y); o.z = f2b(v.z); o.w = f2b(v.w);
        *(ushort4*)(Ar + c * 4) = o;
    } else {
        ushort4 z; z.x = 0; z.y = 0; z.z = 0; z.w = 0;
        *(ushort4*)(Ar + c * 4) = z;
        if (c == 0) perm[r] = -1;     // mark pad row
    }
}

// ---------------- K6: grouped GEMM, 128x128 tile, mfma_f32_16x16x32_bf16 ----------------
// LDS row stride 56 ushorts = 112 B = 7 x 16B-chunks: fragment reads and staging
// writes both spread evenly across the 8 LDS super-banks (2-way max = free).
constexpr int kBK  = 32;
constexpr int kLDP = 56;

__global__ __launch_bounds__(256, 2) void k_gemm(const unsigned short* __restrict__ A,
                                                 const unsigned short* __restrict__ Wt,
                                                 const float* __restrict__ eb,
                                                 const int* __restrict__ perm,
                                                 const float* __restrict__ gate,
                                                 const int* __restrict__ tile_e,
                                                 const int* __restrict__ tile_row,
                                                 float* __restrict__ out) {
    int bm = blockIdx.x, bn = blockIdx.y;
    int e = tile_e[bm];
    if (e < 0) return;
    int rowbase = tile_row[bm];

    __shared__ __align__(16) unsigned short As[128 * kLDP];
    __shared__ __align__(16) unsigned short Bs[128 * kLDP];

    int tid = threadIdx.x;
    int wave = tid >> 6, lane = tid & 63;
    int wm = wave & 1, wn = wave >> 1;           // 2x2 waves over 128x128
    int quad = lane >> 4, l15 = lane & 15;

    floatx4 acc[4][4];
#pragma unroll
    for (int i = 0; i < 4; ++i)
#pragma unroll
        for (int j = 0; j < 4; ++j) acc[i][j] = floatx4{0.f, 0.f, 0.f, 0.f};

    const unsigned short* Ab = A + (size_t)rowbase * kH;
    const unsigned short* Bb = Wt + ((size_t)e << 20) + (size_t)(bn * 128) * kH;

    // staging: 512 16B-chunks/tile, chunk c -> row=c>>2, seg=c&3
    int c0 = tid, c1 = tid + 256;
    int r0 = c0 >> 2, s0 = c0 & 3;
    int r1 = c1 >> 2, s1 = c1 & 3;

    for (int k0 = 0; k0 < kH; k0 += kBK) {
        uint4 a0 = *(const uint4*)(Ab + (size_t)r0 * kH + k0 + s0 * 8);
        uint4 a1 = *(const uint4*)(Ab + (size_t)r1 * kH + k0 + s1 * 8);
        uint4 b0 = *(const uint4*)(Bb + (size_t)r0 * kH + k0 + s0 * 8);
        uint4 b1 = *(const uint4*)(Bb + (size_t)r1 * kH + k0 + s1 * 8);
        __syncthreads();   // prior iter's LDS reads complete
        *(uint4*)&As[r0 * kLDP + s0 * 8] = a0;
        *(uint4*)&As[r1 * kLDP + s1 * 8] = a1;
        *(uint4*)&Bs[r0 * kLDP + s0 * 8] = b0;
        *(uint4*)&Bs[r1 * kLDP + s1 * 8] = b1;
        __syncthreads();

        short8 af[4], bf[4];
#pragma unroll
        for (int i = 0; i < 4; ++i)
            af[i] = *(const short8*)&As[(wm * 64 + i * 16 + l15) * kLDP + quad * 8];
#pragma unroll
        for (int i = 0; i < 4; ++i)
            bf[i] = *(const short8*)&Bs[(wn * 64 + i * 16 + l15) * kLDP + quad * 8];
#pragma unroll
        for (int i = 0; i < 4; ++i)
#pragma unroll
            for (int j = 0; j < 4; ++j)
                acc[i][j] = __builtin_amdgcn_mfma_f32_16x16x32_bf16(af[i], bf[j], acc[i][j], 0, 0, 0);
    }

    // epilogue: C row = quad*4 + reg, col = lane&15 (verified m89/m91 mapping)
    int colbase = bn * 128 + wn * 64;
#pragma unroll
    for (int i = 0; i < 4; ++i) {
        int rl = rowbase + wm * 64 + i * 16 + quad * 4;
#pragma unroll
        for (int rg = 0; rg < 4; ++rg) {
            int r = rl + rg;
            int tok = perm[r];
            if (tok < 0) continue;          // pad row
            float g = gate[tok];
            float* op = out + (size_t)tok * kH;
#pragma unroll
            for (int j = 0; j < 4; ++j) {
                int col = colbase + j * 16 + l15;
                op[col] = g * (acc[i][j][rg] + eb[e * kH + col]);
            }
        }
    }
}

extern "C" void kernel_launch(void* const* d_in, const int* in_sizes, int n_in,
                              void* d_out, int out_size, void* d_ws, size_t ws_size,
                              hipStream_t stream) {
    const float* x  = (const float*)d_in[0];   // [T,H]
    const float* rw = (const float*)d_in[1];   // [H,E]
    const float* rb = (const float*)d_in[2];   // [E]
    const float* ew = (const float*)d_in[3];   // [E,H,H]
    const float* eb = (const float*)d_in[4];   // [E,H]
    float* out = (float*)d_out;                // [T,H]

    char* p = (char*)d_ws;
    unsigned short* Wt = (unsigned short*)p; p += (size_t)kE * kH * kH * 2;   // 16 MB
    unsigned short* A  = (unsigned short*)p; p += (size_t)kMaxRows * kH * 2;  // 18 MB
    float* gate = (float*)p; p += (size_t)kT * 4;
    int* idx    = (int*)p;   p += (size_t)kT * 4;
    int* rank   = (int*)p;   p += (size_t)kT * 4;
    int* perm   = (int*)p;   p += (size_t)kMaxRows * 4;
    int* cnt    = (int*)p;   p += 64;
    int* aoff   = (int*)p;   p += 64;
    int* tile_e = (int*)p;   p += kMaxTiles * 4;
    int* tile_r = (int*)p;   p += kMaxTiles * 4;

    k_zero_cnt<<<1, 64, 0, stream>>>(cnt);
    dim3 tg(kH / 64, kH / 64, kE);
    k_transpose_w<<<tg, 256, 0, stream>>>(ew, Wt);
    k_router<<<kT / 32, 256, 0, stream>>>(x, rw, rb, idx, gate, rank, cnt);
    k_scan<<<1, 64, 0, stream>>>(cnt, aoff, tile_e, tile_r);
    k_perm<<<kT / 256, 256, 0, stream>>>(idx, rank, aoff, perm);
    k_gather<<<kMaxRows, 256, 0, stream>>>(x, aoff, cnt, perm, A);
    dim3 gg(kMaxTiles, kH / 128);
    k_gemm<<<gg, 256, 0, stream>>>(A, Wt, eb, perm, gate, tile_e, tile_r, out);
}

// Round 3
// 215.324 us; speedup vs baseline: 1.0449x; 1.0449x over previous
//
#include <hip/hip_runtime.h>

// Problem constants (B=4, S=2048 -> T=8192 tokens; H=1024; E=8 experts)
constexpr int kT = 8192;
constexpr int kH = 1024;
constexpr int kE = 8;
constexpr int kMaxRows  = 9216;   // kT + kE*128 (per-expert 128-padding worst case)
constexpr int kMaxTiles = 72;     // kT/128 + kE
constexpr int kNS  = 8;           // router H-split
constexpr int kSeg = kH / kNS;    // 128

typedef short short8 __attribute__((ext_vector_type(8)));
typedef float floatx4 __attribute__((ext_vector_type(4)));

__device__ inline unsigned short f2b(float f) {
    union { float f; unsigned int u; } v; v.f = f;
    unsigned int r = v.u + 0x7FFFu + ((v.u >> 16) & 1u);  // round-to-nearest-even
    return (unsigned short)(r >> 16);
}

#define GLDS16(gp, lp)                                                                  \
    __builtin_amdgcn_global_load_lds(                                                   \
        (const __attribute__((address_space(1))) unsigned int*)(gp),                    \
        (__attribute__((address_space(3))) unsigned int*)(lp), 16, 0, 0)

// ---------------- K1: transpose+convert expert_w [E][k][n] f32 -> Wt [E][n][k] bf16 ----
// (also zeros the expert counters from block 0 — saves a launch)
__global__ __launch_bounds__(256) void k_transpose_w(const float* __restrict__ W,
                                                     unsigned short* __restrict__ Wt,
                                                     int* __restrict__ cnt) {
    if (blockIdx.x == 0 && blockIdx.y == 0 && blockIdx.z == 0 && threadIdx.x < kE)
        cnt[threadIdx.x] = 0;
    __shared__ float lds[64][65];   // odd stride: conflict-free scalar access both phases
    int kb = blockIdx.x, nb = blockIdx.y, e = blockIdx.z;
    int tid = threadIdx.x;
    int rr = tid >> 4, c4 = tid & 15;
    const float* Wp = W + ((size_t)e << 20) + (size_t)(kb * 64) * kH + nb * 64;
#pragma unroll
    for (int p = 0; p < 4; ++p) {
        int r = p * 16 + rr;  // local k
        float4 v = *(const float4*)(Wp + (size_t)r * kH + c4 * 4);
        lds[r][c4 * 4 + 0] = v.x; lds[r][c4 * 4 + 1] = v.y;
        lds[r][c4 * 4 + 2] = v.z; lds[r][c4 * 4 + 3] = v.w;
    }
    __syncthreads();
    unsigned short* Wo = Wt + ((size_t)e << 20) + (size_t)(nb * 64) * kH + kb * 64;
#pragma unroll
    for (int p = 0; p < 4; ++p) {
        int n = p * 16 + rr;  // local n
        ushort4 o;
        o.x = f2b(lds[c4 * 4 + 0][n]);
        o.y = f2b(lds[c4 * 4 + 1][n]);
        o.z = f2b(lds[c4 * 4 + 2][n]);
        o.w = f2b(lds[c4 * 4 + 3][n]);
        *(ushort4*)(Wo + (size_t)n * kH + c4 * 4) = o;
    }
}

// ---------------- K2a: router partial logits, H split 8-ways for occupancy ----------------
// One wave = 8 tokens x 8 experts over one 128-wide H segment. fp32 throughout
// (bf16 logits risk argmax flips = full-magnitude output errors).
__global__ __launch_bounds__(256) void k_router_partial(const float* __restrict__ x,
                                                        const float* __restrict__ rw,
                                                        float* __restrict__ plog) {
    int wave = blockIdx.x * 4 + (threadIdx.x >> 6);
    int lane = threadIdx.x & 63;
    int tg = lane >> 3, e = lane & 7;
    int t = wave * 8 + tg;
    int seg = blockIdx.y;
    const float* xp = x + (size_t)t * kH + seg * kSeg;
    const float* wp = rw + (size_t)seg * kSeg * kE + e;
    float a0 = 0.f, a1 = 0.f;
#pragma unroll 4
    for (int i = 0; i < kSeg / 8; ++i) {
        float4 v0 = *(const float4*)(xp + i * 8);
        float4 v1 = *(const float4*)(xp + i * 8 + 4);
        a0 += v0.x * wp[(i * 8 + 0) * kE];
        a0 += v0.y * wp[(i * 8 + 1) * kE];
        a0 += v0.z * wp[(i * 8 + 2) * kE];
        a0 += v0.w * wp[(i * 8 + 3) * kE];
        a1 += v1.x * wp[(i * 8 + 4) * kE];
        a1 += v1.y * wp[(i * 8 + 5) * kE];
        a1 += v1.z * wp[(i * 8 + 6) * kE];
        a1 += v1.w * wp[(i * 8 + 7) * kE];
    }
    plog[(size_t)t * 64 + e * 8 + seg] = a0 + a1;
}

// ---------------- K2b: reduce partials -> softmax/argmax/gate/rank ----------------
__global__ __launch_bounds__(256) void k_router_final(const float* __restrict__ plog,
                                                      const float* __restrict__ rb,
                                                      int* __restrict__ idx, float* __restrict__ gate,
                                                      int* __restrict__ rank, int* __restrict__ cnt) {
    int wave = blockIdx.x * 4 + (threadIdx.x >> 6);
    int lane = threadIdx.x & 63;
    int tg = lane >> 3, e = lane & 7;
    int t = wave * 8 + tg;
    const float* pp = plog + (size_t)t * 64 + e * 8;
    float4 p0 = *(const float4*)pp;
    float4 p1 = *(const float4*)(pp + 4);
    float acc = rb[e] + ((p0.x + p0.y) + (p0.z + p0.w)) + ((p1.x + p1.y) + (p1.z + p1.w));
    // argmax over the 8 expert lanes (first-max tie-break like np.argmax)
    float m = acc; int bi = e;
#pragma unroll
    for (int s = 1; s < 8; s <<= 1) {
        float om = __shfl_xor(m, s);
        int   ob = __shfl_xor(bi, s);
        if (om > m || (om == m && ob < bi)) { m = om; bi = ob; }
    }
    float p = __expf(acc - m);
    float sum = p;
#pragma unroll
    for (int s = 1; s < 8; s <<= 1) sum += __shfl_xor(sum, s);
    if (e == 0) {
        idx[t]  = bi;
        gate[t] = 1.0f / sum;           // softmax prob at argmax
        rank[t] = atomicAdd(&cnt[bi], 1);
    }
}

// ---------------- K3: scan counts -> 128-aligned segment offsets + m-tile table ----------------
__global__ void k_scan(const int* __restrict__ cnt, int* __restrict__ aoff,
                       int* __restrict__ tile_e, int* __restrict__ tile_row) {
    if (threadIdx.x != 0) return;
    int off = 0, tt = 0;
    for (int e = 0; e < kE; ++e) {
        aoff[e] = off;
        int c = cnt[e];
        int nt = (c + 127) >> 7;
        for (int i = 0; i < nt; ++i) { tile_e[tt] = e; tile_row[tt] = off + (i << 7); ++tt; }
        off += nt << 7;
    }
    aoff[kE] = off;
    for (; tt < kMaxTiles; ++tt) tile_e[tt] = -1;
}

// ---------------- K4: build permutation (sorted row -> token) ----------------
__global__ __launch_bounds__(256) void k_perm(const int* __restrict__ idx,
                                              const int* __restrict__ rank,
                                              const int* __restrict__ aoff,
                                              int* __restrict__ perm) {
    int t = blockIdx.x * 256 + threadIdx.x;
    perm[aoff[idx[t]] + rank[t]] = t;
}

// ---------------- K5: gather tokens into sorted bf16 A; zero pad rows ----------------
__global__ __launch_bounds__(256) void k_gather(const float* __restrict__ x,
                                                const int* __restrict__ aoff,
                                                const int* __restrict__ cnt,
                                                int* __restrict__ perm,
                                                unsigned short* __restrict__ A) {
    int r = blockIdx.x;
    if (r >= aoff[kE]) return;
    int e = 0;
    while (r >= aoff[e + 1]) ++e;     // block-uniform, <=8 iters
    int local = r - aoff[e];
    int c = threadIdx.x;
    unsigned short* Ar = A + (size_t)r * kH;
    if (local < cnt[e]) {
        int tok = perm[r];
        const float* xp = x + (size_t)tok * kH;
        float4 v = *(const float4*)(xp + c * 4);
        ushort4 o; o.x = f2b(v.x); o.y = f2b(v.y); o.z = f2b(v.z); o.w = f2b(v.w);
        *(ushort4*)(Ar + c * 4) = o;
    } else {
        ushort4 z; z.x = 0; z.y = 0; z.z = 0; z.w = 0;
        *(ushort4*)(Ar + c * 4) = z;
        if (c == 0) perm[r] = -1;     // mark pad row
    }
}

// ---------------- K6: grouped GEMM, 128x128 tile, mfma_f32_16x16x32_bf16 ----------------
// Staging via global_load_lds width=16 (m93->m97: 517->874 TF step). LDS rows are
// unpadded 64 B (wave-uniform base + lane*16 dest requirement); a 16B-chunk XOR
// swizzle (seg ^= row&3) caps fragment-read bank aliasing at 4-way.
constexpr int kBK = 32;

__global__ __launch_bounds__(256, 2) void k_gemm(const unsigned short* __restrict__ A,
                                                 const unsigned short* __restrict__ Wt,
                                                 const float* __restrict__ eb,
                                                 const int* __restrict__ perm,
                                                 const float* __restrict__ gate,
                                                 const int* __restrict__ tile_e,
                                                 const int* __restrict__ tile_row,
                                                 float* __restrict__ out) {
    int bm = blockIdx.x, bn = blockIdx.y;
    int e = tile_e[bm];
    if (e < 0) return;
    int rowbase = tile_row[bm];

    __shared__ __align__(16) unsigned short As[128 * kBK];   // 8 KB
    __shared__ __align__(16) unsigned short Bs[128 * kBK];   // 8 KB

    int tid = threadIdx.x;
    int wave = tid >> 6, lane = tid & 63;
    int wm = wave & 1, wn = wave >> 1;           // 2x2 waves over 128x128
    int quad = lane >> 4, l15 = lane & 15;
    int lrow = lane >> 2;                        // 0..15 within a 16-row chunk
    int lseg = (lane & 3) ^ (lrow & 3);          // swizzled global 16B-segment

    floatx4 acc[4][4];
#pragma unroll
    for (int i = 0; i < 4; ++i)
#pragma unroll
        for (int j = 0; j < 4; ++j) acc[i][j] = floatx4{0.f, 0.f, 0.f, 0.f};

    const unsigned short* Ab = A + (size_t)rowbase * kH;
    const unsigned short* Bb = Wt + ((size_t)e << 20) + (size_t)(bn * 128) * kH;

    // wave w stages rows [w*32, w*32+32) of both tiles: 2 issues of 16 rows each
    const unsigned short* aP0 = Ab + (size_t)(wave * 32 + lrow) * kH + lseg * 8;
    const unsigned short* aP1 = aP0 + (size_t)16 * kH;
    const unsigned short* bP0 = Bb + (size_t)(wave * 32 + lrow) * kH + lseg * 8;
    const unsigned short* bP1 = bP0 + (size_t)16 * kH;
    unsigned short* lA0 = &As[(wave * 32) * kBK];
    unsigned short* lA1 = &As[(wave * 32 + 16) * kBK];
    unsigned short* lB0 = &Bs[(wave * 32) * kBK];
    unsigned short* lB1 = &Bs[(wave * 32 + 16) * kBK];

    int sw = (quad ^ (l15 & 3)) * 8;             // fragment-read swizzled seg (row&3 == l15&3)

    for (int k0 = 0; k0 < kH; k0 += kBK) {
        __syncthreads();                         // prior iter's fragment reads complete
        GLDS16(aP0 + k0, lA0);
        GLDS16(aP1 + k0, lA1);
        GLDS16(bP0 + k0, lB0);
        GLDS16(bP1 + k0, lB1);
        __syncthreads();                         // drains vmcnt -> tile visible

        short8 af[4], bf[4];
#pragma unroll
        for (int i = 0; i < 4; ++i)
            af[i] = *(const short8*)&As[(wm * 64 + i * 16 + l15) * kBK + sw];
#pragma unroll
        for (int i = 0; i < 4; ++i)
            bf[i] = *(const short8*)&Bs[(wn * 64 + i * 16 + l15) * kBK + sw];
#pragma unroll
        for (int i = 0; i < 4; ++i)
#pragma unroll
            for (int j = 0; j < 4; ++j)
                acc[i][j] = __builtin_amdgcn_mfma_f32_16x16x32_bf16(af[i], bf[j], acc[i][j], 0, 0, 0);
    }

    // epilogue: C row = quad*4 + reg, col = lane&15 (verified m89/m91 mapping)
    int colbase = bn * 128 + wn * 64;
#pragma unroll
    for (int i = 0; i < 4; ++i) {
        int rl = rowbase + wm * 64 + i * 16 + quad * 4;
#pragma unroll
        for (int rg = 0; rg < 4; ++rg) {
            int r = rl + rg;
            int tok = perm[r];
            if (tok < 0) continue;          // pad row
            float g = gate[tok];
            float* op = out + (size_t)tok * kH;
#pragma unroll
            for (int j = 0; j < 4; ++j) {
                int col = colbase + j * 16 + l15;
                op[col] = g * (acc[i][j][rg] + eb[e * kH + col]);
            }
        }
    }
}

extern "C" void kernel_launch(void* const* d_in, const int* in_sizes, int n_in,
                              void* d_out, int out_size, void* d_ws, size_t ws_size,
                              hipStream_t stream) {
    const float* x  = (const float*)d_in[0];   // [T,H]
    const float* rw = (const float*)d_in[1];   // [H,E]
    const float* rb = (const float*)d_in[2];   // [E]
    const float* ew = (const float*)d_in[3];   // [E,H,H]
    const float* eb = (const float*)d_in[4];   // [E,H]
    float* out = (float*)d_out;                // [T,H]

    char* p = (char*)d_ws;
    unsigned short* Wt = (unsigned short*)p; p += (size_t)kE * kH * kH * 2;   // 16 MB
    unsigned short* A  = (unsigned short*)p; p += (size_t)kMaxRows * kH * 2;  // 18 MB
    float* plog = (float*)p; p += (size_t)kT * 64 * 4;                        // 2 MB
    float* gate = (float*)p; p += (size_t)kT * 4;
    int* idx    = (int*)p;   p += (size_t)kT * 4;
    int* rank   = (int*)p;   p += (size_t)kT * 4;
    int* perm   = (int*)p;   p += (size_t)kMaxRows * 4;
    int* cnt    = (int*)p;   p += 64;
    int* aoff   = (int*)p;   p += 64;
    int* tile_e = (int*)p;   p += kMaxTiles * 4;
    int* tile_r = (int*)p;   p += kMaxTiles * 4;

    dim3 tg(kH / 64, kH / 64, kE);
    k_transpose_w<<<tg, 256, 0, stream>>>(ew, Wt, cnt);
    dim3 rg(kT / 32, kNS);
    k_router_partial<<<rg, 256, 0, stream>>>(x, rw, plog);
    k_router_final<<<kT / 32, 256, 0, stream>>>(plog, rb, idx, gate, rank, cnt);
    k_scan<<<1, 64, 0, stream>>>(cnt, aoff, tile_e, tile_r);
    k_perm<<<kT / 256, 256, 0, stream>>>(idx, rank, aoff, perm);
    k_gather<<<kMaxRows, 256, 0, stream>>>(x, aoff, cnt, perm, A);
    dim3 gg(kMaxTiles, kH / 128);
    k_gemm<<<gg, 256, 0, stream>>>(A, Wt, eb, perm, gate, tile_e, tile_r, out);
}

// Round 4
// 212.735 us; speedup vs baseline: 1.0577x; 1.0122x over previous
//
#include <hip/hip_runtime.h>

// Problem constants (B=4, S=2048 -> T=8192 tokens; H=1024; E=8 experts)
constexpr int kT = 8192;
constexpr int kH = 1024;
constexpr int kE = 8;
constexpr int kMaxRows  = 9216;   // kT + kE*128 (per-expert 128-padding worst case)
constexpr int kMaxTiles = 72;     // kT/128 + kE
constexpr int kNS  = 8;           // router H-split
constexpr int kSeg = kH / kNS;    // 128

typedef short short8 __attribute__((ext_vector_type(8)));
typedef float floatx4 __attribute__((ext_vector_type(4)));

__device__ inline unsigned short f2b(float f) {
    union { float f; unsigned int u; } v; v.f = f;
    unsigned int r = v.u + 0x7FFFu + ((v.u >> 16) & 1u);  // round-to-nearest-even
    return (unsigned short)(r >> 16);
}

#define GLDS16(gp, lp)                                                                  \
    __builtin_amdgcn_global_load_lds(                                                   \
        (const __attribute__((address_space(1))) unsigned int*)(gp),                    \
        (__attribute__((address_space(3))) unsigned int*)(lp), 16, 0, 0)

// ---------------- K1: fused [weight transpose+bf16] + [router partial logits] ----------
// Blocks 0..2047: transpose expert_w [E][k][n] f32 -> Wt [E][n][k] bf16.
// Blocks 2048..4095: router partial dot-products over one 128-wide H segment.
// Both are BW-bound; fusing lets them overlap across CUs instead of serializing.
__global__ __launch_bounds__(256) void k_prep(const float* __restrict__ W,
                                              unsigned short* __restrict__ Wt,
                                              const float* __restrict__ x,
                                              const float* __restrict__ rw,
                                              float* __restrict__ plog,
                                              int* __restrict__ cnt,
                                              int* __restrict__ done) {
    __shared__ float lds[64][65];   // transpose path only; odd stride = conflict-free
    int bid = blockIdx.x;
    int tid = threadIdx.x;
    if (bid == 0 && tid < kE + 1) {            // zero cnt[0..7] and done flag
        if (tid < kE) cnt[tid] = 0; else *done = 0;
    }
    if (bid < 2048) {
        // ---- transpose path ----
        int kb = bid & 15, nb = (bid >> 4) & 15, e = bid >> 8;
        int rr = tid >> 4, c4 = tid & 15;
        const float* Wp = W + ((size_t)e << 20) + (size_t)(kb * 64) * kH + nb * 64;
#pragma unroll
        for (int p = 0; p < 4; ++p) {
            int r = p * 16 + rr;  // local k
            float4 v = *(const float4*)(Wp + (size_t)r * kH + c4 * 4);
            lds[r][c4 * 4 + 0] = v.x; lds[r][c4 * 4 + 1] = v.y;
            lds[r][c4 * 4 + 2] = v.z; lds[r][c4 * 4 + 3] = v.w;
        }
        __syncthreads();
        unsigned short* Wo = Wt + ((size_t)e << 20) + (size_t)(nb * 64) * kH + kb * 64;
#pragma unroll
        for (int p = 0; p < 4; ++p) {
            int n = p * 16 + rr;  // local n
            ushort4 o;
            o.x = f2b(lds[c4 * 4 + 0][n]);
            o.y = f2b(lds[c4 * 4 + 1][n]);
            o.z = f2b(lds[c4 * 4 + 2][n]);
            o.w = f2b(lds[c4 * 4 + 3][n]);
            *(ushort4*)(Wo + (size_t)n * kH + c4 * 4) = o;
        }
    } else {
        // ---- router partial path: one wave = 8 tokens x 8 experts, fp32 ----
        int rb = bid - 2048;
        int seg = rb >> 8;
        int wave = (rb & 255) * 4 + (tid >> 6);
        int lane = tid & 63;
        int tg = lane >> 3, e = lane & 7;
        int t = wave * 8 + tg;
        const float* xp = x + (size_t)t * kH + seg * kSeg;
        const float* wp = rw + (size_t)seg * kSeg * kE + e;
        float a0 = 0.f, a1 = 0.f;
#pragma unroll 4
        for (int i = 0; i < kSeg / 8; ++i) {
            float4 v0 = *(const float4*)(xp + i * 8);
            float4 v1 = *(const float4*)(xp + i * 8 + 4);
            a0 += v0.x * wp[(i * 8 + 0) * kE];
            a0 += v0.y * wp[(i * 8 + 1) * kE];
            a0 += v0.z * wp[(i * 8 + 2) * kE];
            a0 += v0.w * wp[(i * 8 + 3) * kE];
            a1 += v1.x * wp[(i * 8 + 4) * kE];
            a1 += v1.y * wp[(i * 8 + 5) * kE];
            a1 += v1.z * wp[(i * 8 + 6) * kE];
            a1 += v1.w * wp[(i * 8 + 7) * kE];
        }
        plog[(size_t)t * 64 + e * 8 + seg] = a0 + a1;
    }
}

// ---------------- K2: router finalize (softmax/argmax/gate/rank) + last-block scan ----
__global__ __launch_bounds__(256) void k_router_final(const float* __restrict__ plog,
                                                      const float* __restrict__ rb,
                                                      int* __restrict__ idx, float* __restrict__ gate,
                                                      int* __restrict__ rank, int* __restrict__ cnt,
                                                      int* __restrict__ done,
                                                      int* __restrict__ aoff,
                                                      int* __restrict__ tile_e,
                                                      int* __restrict__ tile_row) {
    int wave = blockIdx.x * 4 + (threadIdx.x >> 6);
    int lane = threadIdx.x & 63;
    int tg = lane >> 3, e = lane & 7;
    int t = wave * 8 + tg;
    const float* pp = plog + (size_t)t * 64 + e * 8;
    float4 p0 = *(const float4*)pp;
    float4 p1 = *(const float4*)(pp + 4);
    float acc = rb[e] + ((p0.x + p0.y) + (p0.z + p0.w)) + ((p1.x + p1.y) + (p1.z + p1.w));
    // argmax over the 8 expert lanes (first-max tie-break like np.argmax)
    float m = acc; int bi = e;
#pragma unroll
    for (int s = 1; s < 8; s <<= 1) {
        float om = __shfl_xor(m, s);
        int   ob = __shfl_xor(bi, s);
        if (om > m || (om == m && ob < bi)) { m = om; bi = ob; }
    }
    float p = __expf(acc - m);
    float sum = p;
#pragma unroll
    for (int s = 1; s < 8; s <<= 1) sum += __shfl_xor(sum, s);
    if (e == 0) {
        idx[t]  = bi;
        gate[t] = 1.0f / sum;           // softmax prob at argmax
        rank[t] = atomicAdd(&cnt[bi], 1);
    }
    // ---- last block to finish performs the (tiny) scan ----
    __syncthreads();
    if (threadIdx.x == 0) {
        __threadfence();
        int old = atomicAdd(done, 1);
        if (old == (int)gridDim.x - 1) {
            __threadfence();
            int off = 0, tt = 0;
            for (int ee = 0; ee < kE; ++ee) {
                aoff[ee] = off;
                int c = atomicAdd(&cnt[ee], 0);   // device-coherent read
                int nt = (c + 127) >> 7;
                for (int i = 0; i < nt; ++i) { tile_e[tt] = ee; tile_row[tt] = off + (i << 7); ++tt; }
                off += nt << 7;
            }
            aoff[kE] = off;
            for (; tt < kMaxTiles; ++tt) tile_e[tt] = -1;
        }
    }
}

// ---------------- K3: fused perm-build + gather (token blocks) + pad-zero (row blocks) --
__global__ __launch_bounds__(256) void k_gather(const float* __restrict__ x,
                                                const float* __restrict__ gate,
                                                const int* __restrict__ idx,
                                                const int* __restrict__ rank,
                                                const int* __restrict__ aoff,
                                                const int* __restrict__ cnt,
                                                int* __restrict__ perm,
                                                float* __restrict__ grow,
                                                unsigned short* __restrict__ A) {
    int bid = blockIdx.x;
    int c = threadIdx.x;
    if (bid < kT) {
        // token block: compute destination row directly (no separate perm pass)
        int t = bid;
        int e = idx[t];
        int row = aoff[e] + rank[t];
        const float* xp = x + (size_t)t * kH;
        float4 v = *(const float4*)(xp + c * 4);
        ushort4 o; o.x = f2b(v.x); o.y = f2b(v.y); o.z = f2b(v.z); o.w = f2b(v.w);
        *(ushort4*)(A + (size_t)row * kH + c * 4) = o;
        if (c == 0) { perm[row] = t; grow[row] = gate[t]; }
    } else {
        // pad block: zero rows in [cnt[e], segment end)
        int r = bid - kT;
        if (r >= aoff[kE]) return;
        int e = 0;
        while (r >= aoff[e + 1]) ++e;     // block-uniform, <=8 iters
        if (r - aoff[e] < cnt[e]) return; // real row, token block handles it
        ushort4 z; z.x = 0; z.y = 0; z.z = 0; z.w = 0;
        *(ushort4*)(A + (size_t)r * kH + c * 4) = z;
        if (c == 0) perm[r] = -1;
    }
}

// ---------------- K4: grouped GEMM, 128x128 tile, BK=64, mfma_f32_16x16x32_bf16 --------
// BK=64 halves the barrier count vs BK=32 (16 iters): the structural vmcnt-drain
// stall at each __syncthreads amortizes over 2x the MFMA. 32 KB LDS still allows
// >=2 blocks/CU (grid-limited at 2 anyway). Rows are 128 B (8 x 16B chunks);
// chunk-XOR swizzle (seg ^= row&7) keeps fragment reads at the 8-lane/bank-group floor.
constexpr int kBK = 64;

__global__ __launch_bounds__(256, 2) void k_gemm(const unsigned short* __restrict__ A,
                                                 const unsigned short* __restrict__ Wt,
                                                 const float* __restrict__ eb,
                                                 const int* __restrict__ perm,
                                                 const float* __restrict__ grow,
                                                 const int* __restrict__ tile_e,
                                                 const int* __restrict__ tile_row,
                                                 float* __restrict__ out) {
    int bm = blockIdx.x, bn = blockIdx.y;
    int e = tile_e[bm];
    if (e < 0) return;
    int rowbase = tile_row[bm];

    __shared__ __align__(16) unsigned short As[128 * kBK];   // 16 KB
    __shared__ __align__(16) unsigned short Bs[128 * kBK];   // 16 KB

    int tid = threadIdx.x;
    int wave = tid >> 6, lane = tid & 63;
    int wm = wave & 1, wn = wave >> 1;           // 2x2 waves over 128x128
    int quad = lane >> 4, l15 = lane & 15;

    floatx4 acc[4][4];
#pragma unroll
    for (int i = 0; i < 4; ++i)
#pragma unroll
        for (int j = 0; j < 4; ++j) acc[i][j] = floatx4{0.f, 0.f, 0.f, 0.f};

    const unsigned short* Ab = A + (size_t)rowbase * kH;
    const unsigned short* Bb = Wt + ((size_t)e << 20) + (size_t)(bn * 128) * kH;

    // staging: wave stages rows [wave*32, wave*32+32), 4 issues of 8 rows each.
    // lane -> row (lane>>3), chunk ((lane&7)^(lane>>3)) : LDS[r][s] = G[r][s^(r&7)]
    int lrow8 = lane >> 3;                       // 0..7
    int lseg8 = (lane & 7) ^ lrow8;              // swizzled 16B chunk
    const unsigned short* aP = Ab + (size_t)(wave * 32 + lrow8) * kH + lseg8 * 8;
    const unsigned short* bP = Bb + (size_t)(wave * 32 + lrow8) * kH + lseg8 * 8;
    unsigned short* lA = &As[(wave * 32) * kBK];
    unsigned short* lB = &Bs[(wave * 32) * kBK];

    // fragment read chunk: global seg g = ks*4+quad at row l15 -> LDS seg g^(l15&7)
    int sw0 = ((0 * 4 + quad) ^ (l15 & 7)) * 8;
    int sw1 = ((1 * 4 + quad) ^ (l15 & 7)) * 8;

    for (int k0 = 0; k0 < kH; k0 += kBK) {
        __syncthreads();                         // prior iter's fragment reads complete
#pragma unroll
        for (int j = 0; j < 4; ++j) {
            GLDS16(aP + (size_t)(j * 8) * kH + k0, lA + j * 8 * kBK);
            GLDS16(bP + (size_t)(j * 8) * kH + k0, lB + j * 8 * kBK);
        }
        __syncthreads();                         // drains vmcnt -> tile visible

        short8 af[4][2], bf[4][2];
#pragma unroll
        for (int i = 0; i < 4; ++i) {
            int r = (wm * 64 + i * 16 + l15) * kBK;
            af[i][0] = *(const short8*)&As[r + sw0];
            af[i][1] = *(const short8*)&As[r + sw1];
        }
#pragma unroll
        for (int i = 0; i < 4; ++i) {
            int r = (wn * 64 + i * 16 + l15) * kBK;
            bf[i][0] = *(const short8*)&Bs[r + sw0];
            bf[i][1] = *(const short8*)&Bs[r + sw1];
        }
#pragma unroll
        for (int ks = 0; ks < 2; ++ks)
#pragma unroll
            for (int i = 0; i < 4; ++i)
#pragma unroll
                for (int j = 0; j < 4; ++j)
                    acc[i][j] = __builtin_amdgcn_mfma_f32_16x16x32_bf16(af[i][ks], bf[j][ks],
                                                                        acc[i][j], 0, 0, 0);
    }

    // epilogue: C row = quad*4 + reg, col = lane&15 (verified m89/m91 mapping)
    int colbase = bn * 128 + wn * 64;
#pragma unroll
    for (int i = 0; i < 4; ++i) {
        int rl = rowbase + wm * 64 + i * 16 + quad * 4;
#pragma unroll
        for (int rg = 0; rg < 4; ++rg) {
            int r = rl + rg;
            int tok = perm[r];
            if (tok < 0) continue;          // pad row
            float g = grow[r];
            float* op = out + (size_t)tok * kH;
#pragma unroll
            for (int j = 0; j < 4; ++j) {
                int col = colbase + j * 16 + l15;
                op[col] = g * (acc[i][j][rg] + eb[e * kH + col]);
            }
        }
    }
}

extern "C" void kernel_launch(void* const* d_in, const int* in_sizes, int n_in,
                              void* d_out, int out_size, void* d_ws, size_t ws_size,
                              hipStream_t stream) {
    const float* x  = (const float*)d_in[0];   // [T,H]
    const float* rw = (const float*)d_in[1];   // [H,E]
    const float* rb = (const float*)d_in[2];   // [E]
    const float* ew = (const float*)d_in[3];   // [E,H,H]
    const float* eb = (const float*)d_in[4];   // [E,H]
    float* out = (float*)d_out;                // [T,H]

    char* p = (char*)d_ws;
    unsigned short* Wt = (unsigned short*)p; p += (size_t)kE * kH * kH * 2;   // 16 MB
    unsigned short* A  = (unsigned short*)p; p += (size_t)kMaxRows * kH * 2;  // 18 MB
    float* plog = (float*)p; p += (size_t)kT * 64 * 4;                        // 2 MB
    float* gate = (float*)p; p += (size_t)kT * 4;
    float* grow = (float*)p; p += (size_t)kMaxRows * 4;
    int* idx    = (int*)p;   p += (size_t)kT * 4;
    int* rank   = (int*)p;   p += (size_t)kT * 4;
    int* perm   = (int*)p;   p += (size_t)kMaxRows * 4;
    int* cnt    = (int*)p;   p += 64;
    int* aoff   = (int*)p;   p += 64;
    int* done   = (int*)p;   p += 64;
    int* tile_e = (int*)p;   p += kMaxTiles * 4;
    int* tile_r = (int*)p;   p += kMaxTiles * 4;

    k_prep<<<4096, 256, 0, stream>>>(ew, Wt, x, rw, plog, cnt, done);
    k_router_final<<<kT / 32, 256, 0, stream>>>(plog, rb, idx, gate, rank, cnt, done,
                                                aoff, tile_e, tile_r);
    k_gather<<<kT + kMaxRows, 256, 0, stream>>>(x, gate, idx, rank, aoff, cnt, perm, grow, A);
    dim3 gg(kMaxTiles, kH / 128);
    k_gemm<<<gg, 256, 0, stream>>>(A, Wt, eb, perm, grow, tile_e, tile_r, out);
}

// Round 5
// 184.210 us; speedup vs baseline: 1.2214x; 1.1549x over previous
//
#include <hip/hip_runtime.h>

// Problem constants (B=4, S=2048 -> T=8192 tokens; H=1024; E=8 experts)
constexpr int kT = 8192;
constexpr int kH = 1024;
constexpr int kE = 8;
constexpr int kMaxRows  = 9216;   // kT + kE*128 (per-expert 128-padding worst case)
constexpr int kMaxTiles = 72;     // kT/128 + kE
constexpr int kNS  = 8;           // router H-split
constexpr int kSeg = kH / kNS;    // 128
constexpr int kCntStride = 32;    // pad expert counters to separate 128B cache lines

typedef short short8 __attribute__((ext_vector_type(8)));
typedef float floatx4 __attribute__((ext_vector_type(4)));

__device__ inline unsigned short f2b(float f) {
    union { float f; unsigned int u; } v; v.f = f;
    unsigned int r = v.u + 0x7FFFu + ((v.u >> 16) & 1u);  // round-to-nearest-even
    return (unsigned short)(r >> 16);
}

#define GLDS16(gp, lp)                                                                  \
    __builtin_amdgcn_global_load_lds(                                                   \
        (const __attribute__((address_space(1))) unsigned int*)(gp),                    \
        (__attribute__((address_space(3))) unsigned int*)(lp), 16, 0, 0)

// ---------------- K1: fused [weight transpose+bf16] + [router partial logits] ----------
// Blocks 0..2047: transpose expert_w [E][k][n] f32 -> Wt [E][n][k] bf16.
// Blocks 2048..4095: router partial dot-products over one 128-wide H segment.
// Both are BW-bound; fusing lets them overlap across CUs instead of serializing.
__global__ __launch_bounds__(256) void k_prep(const float* __restrict__ W,
                                              unsigned short* __restrict__ Wt,
                                              const float* __restrict__ x,
                                              const float* __restrict__ rw,
                                              float* __restrict__ plog,
                                              int* __restrict__ cnt,
                                              int* __restrict__ done) {
    __shared__ float lds[64][65];   // transpose path only; odd stride = conflict-free
    int bid = blockIdx.x;
    int tid = threadIdx.x;
    if (bid == 0 && tid < kE + 1) {            // zero padded cnt[] and done flag
        if (tid < kE) cnt[tid * kCntStride] = 0; else *done = 0;
    }
    if (bid < 2048) {
        // ---- transpose path ----
        int kb = bid & 15, nb = (bid >> 4) & 15, e = bid >> 8;
        int rr = tid >> 4, c4 = tid & 15;
        const float* Wp = W + ((size_t)e << 20) + (size_t)(kb * 64) * kH + nb * 64;
#pragma unroll
        for (int p = 0; p < 4; ++p) {
            int r = p * 16 + rr;  // local k
            float4 v = *(const float4*)(Wp + (size_t)r * kH + c4 * 4);
            lds[r][c4 * 4 + 0] = v.x; lds[r][c4 * 4 + 1] = v.y;
            lds[r][c4 * 4 + 2] = v.z; lds[r][c4 * 4 + 3] = v.w;
        }
        __syncthreads();
        unsigned short* Wo = Wt + ((size_t)e << 20) + (size_t)(nb * 64) * kH + kb * 64;
#pragma unroll
        for (int p = 0; p < 4; ++p) {
            int n = p * 16 + rr;  // local n
            ushort4 o;
            o.x = f2b(lds[c4 * 4 + 0][n]);
            o.y = f2b(lds[c4 * 4 + 1][n]);
            o.z = f2b(lds[c4 * 4 + 2][n]);
            o.w = f2b(lds[c4 * 4 + 3][n]);
            *(ushort4*)(Wo + (size_t)n * kH + c4 * 4) = o;
        }
    } else {
        // ---- router partial path: one wave = 8 tokens x 8 experts, fp32 ----
        int rb = bid - 2048;
        int seg = rb >> 8;
        int wave = (rb & 255) * 4 + (tid >> 6);
        int lane = tid & 63;
        int tg = lane >> 3, e = lane & 7;
        int t = wave * 8 + tg;
        const float* xp = x + (size_t)t * kH + seg * kSeg;
        const float* wp = rw + (size_t)seg * kSeg * kE + e;
        float a0 = 0.f, a1 = 0.f;
#pragma unroll 4
        for (int i = 0; i < kSeg / 8; ++i) {
            float4 v0 = *(const float4*)(xp + i * 8);
            float4 v1 = *(const float4*)(xp + i * 8 + 4);
            a0 += v0.x * wp[(i * 8 + 0) * kE];
            a0 += v0.y * wp[(i * 8 + 1) * kE];
            a0 += v0.z * wp[(i * 8 + 2) * kE];
            a0 += v0.w * wp[(i * 8 + 3) * kE];
            a1 += v1.x * wp[(i * 8 + 4) * kE];
            a1 += v1.y * wp[(i * 8 + 5) * kE];
            a1 += v1.z * wp[(i * 8 + 6) * kE];
            a1 += v1.w * wp[(i * 8 + 7) * kE];
        }
        plog[(size_t)t * 64 + e * 8 + seg] = a0 + a1;
    }
}

// ---------------- K2: router finalize (softmax/argmax/gate/rank) + last-block scan ----
// Rank assignment: block-local LDS histogram (contention-free local ranks), then ONE
// global atomic per (block, expert) onto 128B-padded counters. 2048 atomics spread
// over 8 cache lines instead of 8192 onto one line (was 44 us of serialization).
__global__ __launch_bounds__(256) void k_router_final(const float* __restrict__ plog,
                                                      const float* __restrict__ rb,
                                                      int* __restrict__ idx, float* __restrict__ gate,
                                                      int* __restrict__ rank, int* __restrict__ cnt,
                                                      int* __restrict__ done,
                                                      int* __restrict__ aoff,
                                                      int* __restrict__ tile_e,
                                                      int* __restrict__ tile_row) {
    __shared__ int lcnt[kE];
    __shared__ int lbase[kE];
    int tid = threadIdx.x;
    if (tid < kE) lcnt[tid] = 0;
    __syncthreads();

    int wave = blockIdx.x * 4 + (tid >> 6);
    int lane = tid & 63;
    int tg = lane >> 3, e = lane & 7;
    int t = wave * 8 + tg;
    const float* pp = plog + (size_t)t * 64 + e * 8;
    float4 p0 = *(const float4*)pp;
    float4 p1 = *(const float4*)(pp + 4);
    float acc = rb[e] + ((p0.x + p0.y) + (p0.z + p0.w)) + ((p1.x + p1.y) + (p1.z + p1.w));
    // argmax over the 8 expert lanes (first-max tie-break like np.argmax)
    float m = acc; int bi = e;
#pragma unroll
    for (int s = 1; s < 8; s <<= 1) {
        float om = __shfl_xor(m, s);
        int   ob = __shfl_xor(bi, s);
        if (om > m || (om == m && ob < bi)) { m = om; bi = ob; }
    }
    float p = __expf(acc - m);
    float sum = p;
#pragma unroll
    for (int s = 1; s < 8; s <<= 1) sum += __shfl_xor(sum, s);

    int lrank = 0;
    if (e == 0) {
        idx[t]  = bi;
        gate[t] = 1.0f / sum;                       // softmax prob at argmax
        lrank = atomicAdd(&lcnt[bi], 1);            // LDS atomic: local rank
    }
    __syncthreads();
    if (tid < kE) lbase[tid] = atomicAdd(&cnt[tid * kCntStride], lcnt[tid]);
    __syncthreads();
    if (e == 0) rank[t] = lbase[bi] + lrank;        // global rank within expert

    // ---- last block to finish performs the (tiny) scan ----
    __syncthreads();
    if (tid == 0) {
        __threadfence();
        int old = atomicAdd(done, 1);
        if (old == (int)gridDim.x - 1) {
            __threadfence();
            int off = 0, tt = 0;
            for (int ee = 0; ee < kE; ++ee) {
                aoff[ee] = off;
                int c = atomicAdd(&cnt[ee * kCntStride], 0);   // device-coherent read
                int nt = (c + 127) >> 7;
                for (int i = 0; i < nt; ++i) { tile_e[tt] = ee; tile_row[tt] = off + (i << 7); ++tt; }
                off += nt << 7;
            }
            aoff[kE] = off;
            for (; tt < kMaxTiles; ++tt) tile_e[tt] = -1;
        }
    }
}

// ---------------- K3: fused perm-build + gather (token blocks) + pad-zero (row blocks) --
__global__ __launch_bounds__(256) void k_gather(const float* __restrict__ x,
                                                const float* __restrict__ gate,
                                                const int* __restrict__ idx,
                                                const int* __restrict__ rank,
                                                const int* __restrict__ aoff,
                                                const int* __restrict__ cnt,
                                                int* __restrict__ perm,
                                                float* __restrict__ grow,
                                                unsigned short* __restrict__ A) {
    int bid = blockIdx.x;
    int c = threadIdx.x;
    if (bid < kT) {
        // token block: compute destination row directly (no separate perm pass)
        int t = bid;
        int e = idx[t];
        int row = aoff[e] + rank[t];
        const float* xp = x + (size_t)t * kH;
        float4 v = *(const float4*)(xp + c * 4);
        ushort4 o; o.x = f2b(v.x); o.y = f2b(v.y); o.z = f2b(v.z); o.w = f2b(v.w);
        *(ushort4*)(A + (size_t)row * kH + c * 4) = o;
        if (c == 0) { perm[row] = t; grow[row] = gate[t]; }
    } else {
        // pad block: zero rows in [cnt[e], segment end)
        int r = bid - kT;
        if (r >= aoff[kE]) return;
        int e = 0;
        while (r >= aoff[e + 1]) ++e;     // block-uniform, <=8 iters
        if (r - aoff[e] < cnt[e * kCntStride]) return; // real row, token block handles it
        ushort4 z; z.x = 0; z.y = 0; z.z = 0; z.w = 0;
        *(ushort4*)(A + (size_t)r * kH + c * 4) = z;
        if (c == 0) perm[r] = -1;
    }
}

// ---------------- K4: grouped GEMM, 128x128 tile, BK=64, mfma_f32_16x16x32_bf16 --------
// BK=64 halves the barrier count vs BK=32 (16 iters): the structural vmcnt-drain
// stall at each __syncthreads amortizes over 2x the MFMA. 32 KB LDS still allows
// >=2 blocks/CU (grid-limited at 2 anyway). Rows are 128 B (8 x 16B chunks);
// chunk-XOR swizzle (seg ^= row&7) keeps fragment reads at the 8-lane/bank-group floor.
constexpr int kBK = 64;

__global__ __launch_bounds__(256, 2) void k_gemm(const unsigned short* __restrict__ A,
                                                 const unsigned short* __restrict__ Wt,
                                                 const float* __restrict__ eb,
                                                 const int* __restrict__ perm,
                                                 const float* __restrict__ grow,
                                                 const int* __restrict__ tile_e,
                                                 const int* __restrict__ tile_row,
                                                 float* __restrict__ out) {
    int bm = blockIdx.x, bn = blockIdx.y;
    int e = tile_e[bm];
    if (e < 0) return;
    int rowbase = tile_row[bm];

    __shared__ __align__(16) unsigned short As[128 * kBK];   // 16 KB
    __shared__ __align__(16) unsigned short Bs[128 * kBK];   // 16 KB

    int tid = threadIdx.x;
    int wave = tid >> 6, lane = tid & 63;
    int wm = wave & 1, wn = wave >> 1;           // 2x2 waves over 128x128
    int quad = lane >> 4, l15 = lane & 15;

    floatx4 acc[4][4];
#pragma unroll
    for (int i = 0; i < 4; ++i)
#pragma unroll
        for (int j = 0; j < 4; ++j) acc[i][j] = floatx4{0.f, 0.f, 0.f, 0.f};

    const unsigned short* Ab = A + (size_t)rowbase * kH;
    const unsigned short* Bb = Wt + ((size_t)e << 20) + (size_t)(bn * 128) * kH;

    // staging: wave stages rows [wave*32, wave*32+32), 4 issues of 8 rows each.
    // lane -> row (lane>>3), chunk ((lane&7)^(lane>>3)) : LDS[r][s] = G[r][s^(r&7)]
    int lrow8 = lane >> 3;                       // 0..7
    int lseg8 = (lane & 7) ^ lrow8;              // swizzled 16B chunk
    const unsigned short* aP = Ab + (size_t)(wave * 32 + lrow8) * kH + lseg8 * 8;
    const unsigned short* bP = Bb + (size_t)(wave * 32 + lrow8) * kH + lseg8 * 8;
    unsigned short* lA = &As[(wave * 32) * kBK];
    unsigned short* lB = &Bs[(wave * 32) * kBK];

    // fragment read chunk: global seg g = ks*4+quad at row l15 -> LDS seg g^(l15&7)
    int sw0 = ((0 * 4 + quad) ^ (l15 & 7)) * 8;
    int sw1 = ((1 * 4 + quad) ^ (l15 & 7)) * 8;

    for (int k0 = 0; k0 < kH; k0 += kBK) {
        __syncthreads();                         // prior iter's fragment reads complete
#pragma unroll
        for (int j = 0; j < 4; ++j) {
            GLDS16(aP + (size_t)(j * 8) * kH + k0, lA + j * 8 * kBK);
            GLDS16(bP + (size_t)(j * 8) * kH + k0, lB + j * 8 * kBK);
        }
        __syncthreads();                         // drains vmcnt -> tile visible

        short8 af[4][2], bf[4][2];
#pragma unroll
        for (int i = 0; i < 4; ++i) {
            int r = (wm * 64 + i * 16 + l15) * kBK;
            af[i][0] = *(const short8*)&As[r + sw0];
            af[i][1] = *(const short8*)&As[r + sw1];
        }
#pragma unroll
        for (int i = 0; i < 4; ++i) {
            int r = (wn * 64 + i * 16 + l15) * kBK;
            bf[i][0] = *(const short8*)&Bs[r + sw0];
            bf[i][1] = *(const short8*)&Bs[r + sw1];
        }
#pragma unroll
        for (int ks = 0; ks < 2; ++ks)
#pragma unroll
            for (int i = 0; i < 4; ++i)
#pragma unroll
                for (int j = 0; j < 4; ++j)
                    acc[i][j] = __builtin_amdgcn_mfma_f32_16x16x32_bf16(af[i][ks], bf[j][ks],
                                                                        acc[i][j], 0, 0, 0);
    }

    // epilogue: C row = quad*4 + reg, col = lane&15 (verified m89/m91 mapping)
    int colbase = bn * 128 + wn * 64;
#pragma unroll
    for (int i = 0; i < 4; ++i) {
        int rl = rowbase + wm * 64 + i * 16 + quad * 4;
#pragma unroll
        for (int rg = 0; rg < 4; ++rg) {
            int r = rl + rg;
            int tok = perm[r];
            if (tok < 0) continue;          // pad row
            float g = grow[r];
            float* op = out + (size_t)tok * kH;
#pragma unroll
            for (int j = 0; j < 4; ++j) {
                int col = colbase + j * 16 + l15;
                op[col] = g * (acc[i][j][rg] + eb[e * kH + col]);
            }
        }
    }
}

extern "C" void kernel_launch(void* const* d_in, const int* in_sizes, int n_in,
                              void* d_out, int out_size, void* d_ws, size_t ws_size,
                              hipStream_t stream) {
    const float* x  = (const float*)d_in[0];   // [T,H]
    const float* rw = (const float*)d_in[1];   // [H,E]
    const float* rb = (const float*)d_in[2];   // [E]
    const float* ew = (const float*)d_in[3];   // [E,H,H]
    const float* eb = (const float*)d_in[4];   // [E,H]
    float* out = (float*)d_out;                // [T,H]

    char* p = (char*)d_ws;
    unsigned short* Wt = (unsigned short*)p; p += (size_t)kE * kH * kH * 2;   // 16 MB
    unsigned short* A  = (unsigned short*)p; p += (size_t)kMaxRows * kH * 2;  // 18 MB
    float* plog = (float*)p; p += (size_t)kT * 64 * 4;                        // 2 MB
    float* gate = (float*)p; p += (size_t)kT * 4;
    float* grow = (float*)p; p += (size_t)kMaxRows * 4;
    int* idx    = (int*)p;   p += (size_t)kT * 4;
    int* rank   = (int*)p;   p += (size_t)kT * 4;
    int* perm   = (int*)p;   p += (size_t)kMaxRows * 4;
    int* cnt    = (int*)p;   p += kE * kCntStride * 4;   // 128B-padded counters
    int* aoff   = (int*)p;   p += 64;
    int* done   = (int*)p;   p += 64;
    int* tile_e = (int*)p;   p += kMaxTiles * 4;
    int* tile_r = (int*)p;   p += kMaxTiles * 4;

    k_prep<<<4096, 256, 0, stream>>>(ew, Wt, x, rw, plog, cnt, done);
    k_router_final<<<kT / 32, 256, 0, stream>>>(plog, rb, idx, gate, rank, cnt, done,
                                                aoff, tile_e, tile_r);
    k_gather<<<kT + kMaxRows, 256, 0, stream>>>(x, gate, idx, rank, aoff, cnt, perm, grow, A);
    dim3 gg(kMaxTiles, kH / 128);
    k_gemm<<<gg, 256, 0, stream>>>(A, Wt, eb, perm, grow, tile_e, tile_r, out);
}

// Round 6
// 167.886 us; speedup vs baseline: 1.3402x; 1.0972x over previous
//
#include <hip/hip_runtime.h>

// Problem constants (B=4, S=2048 -> T=8192 tokens; H=1024; E=8 experts)
constexpr int kT = 8192;
constexpr int kH = 1024;
constexpr int kE = 8;
constexpr int kMaxTiles = 72;     // kT/128 + kE
constexpr int kNS  = 8;           // router H-split
constexpr int kSeg = kH / kNS;    // 128
constexpr int kCntStride = 32;    // pad expert counters to separate 128B cache lines

typedef short short8 __attribute__((ext_vector_type(8)));
typedef float floatx4 __attribute__((ext_vector_type(4)));

__device__ inline unsigned short f2b(float f) {
    union { float f; unsigned int u; } v; v.f = f;
    unsigned int r = v.u + 0x7FFFu + ((v.u >> 16) & 1u);  // round-to-nearest-even
    return (unsigned short)(r >> 16);
}

#define GLDS16(gp, lp)                                                                  \
    __builtin_amdgcn_global_load_lds(                                                   \
        (const __attribute__((address_space(1))) unsigned int*)(gp),                    \
        (__attribute__((address_space(3))) unsigned int*)(lp), 16, 0, 0)

// ---------------- K1: fused prep, three block ranges ----------------
//   [0,2048)     : transpose expert_w [E][k][n] f32 -> Wt [E][n][k] bf16
//   [2048,6144)  : convert x f32 -> xb bf16 (2 rows/block, fully coalesced)
//   [6144,8192)  : router partial logits, fp32, rw seg-slice transposed into LDS
// All paths BW-or-L2-bound; fused so they overlap across CUs.
__global__ __launch_bounds__(256) void k_prep(const float* __restrict__ W,
                                              unsigned short* __restrict__ Wt,
                                              const float* __restrict__ x,
                                              unsigned short* __restrict__ xb,
                                              const float* __restrict__ rw,
                                              float* __restrict__ plog,
                                              int* __restrict__ cnt,
                                              int* __restrict__ done) {
    __shared__ __align__(16) char smem[16640];   // union: 64x65 f32 | 8x132 f32
    int bid = blockIdx.x;
    int tid = threadIdx.x;
    if (bid == 0 && tid < kE + 1) {              // zero padded cnt[] and done flag
        if (tid < kE) cnt[tid * kCntStride] = 0; else *done = 0;
    }
    if (bid < 2048) {
        // ---- transpose path ----
        float (*lds)[65] = (float(*)[65])smem;
        int kb = bid & 15, nb = (bid >> 4) & 15, e = bid >> 8;
        int rr = tid >> 4, c4 = tid & 15;
        const float* Wp = W + ((size_t)e << 20) + (size_t)(kb * 64) * kH + nb * 64;
#pragma unroll
        for (int p = 0; p < 4; ++p) {
            int r = p * 16 + rr;  // local k
            float4 v = *(const float4*)(Wp + (size_t)r * kH + c4 * 4);
            lds[r][c4 * 4 + 0] = v.x; lds[r][c4 * 4 + 1] = v.y;
            lds[r][c4 * 4 + 2] = v.z; lds[r][c4 * 4 + 3] = v.w;
        }
        __syncthreads();
        unsigned short* Wo = Wt + ((size_t)e << 20) + (size_t)(nb * 64) * kH + kb * 64;
#pragma unroll
        for (int p = 0; p < 4; ++p) {
            int n = p * 16 + rr;  // local n
            ushort4 o;
            o.x = f2b(lds[c4 * 4 + 0][n]);
            o.y = f2b(lds[c4 * 4 + 1][n]);
            o.z = f2b(lds[c4 * 4 + 2][n]);
            o.w = f2b(lds[c4 * 4 + 3][n]);
            *(ushort4*)(Wo + (size_t)n * kH + c4 * 4) = o;
        }
    } else if (bid < 6144) {
        // ---- x -> bf16 path: 2 rows per block, 8 elems/thread, coalesced ----
        int row = (bid - 2048) * 2 + (tid >> 7);
        int col = (tid & 127) * 8;
        const float* xp = x + (size_t)row * kH + col;
        float4 v0 = *(const float4*)xp;
        float4 v1 = *(const float4*)(xp + 4);
        ushort4 o0, o1;
        o0.x = f2b(v0.x); o0.y = f2b(v0.y); o0.z = f2b(v0.z); o0.w = f2b(v0.w);
        o1.x = f2b(v1.x); o1.y = f2b(v1.y); o1.z = f2b(v1.z); o1.w = f2b(v1.w);
        unsigned short* op = xb + (size_t)row * kH + col;
        *(ushort4*)op = o0;
        *(ushort4*)(op + 4) = o1;
    } else {
        // ---- router partial path: one wave = 8 tokens x 8 experts, fp32 ----
        // rw seg-slice staged TRANSPOSED in LDS: rwT[e][h], row pad 132 ->
        // ds_read_b128 rows land 16B apart across 8 experts = conflict-free.
        float (*rwT)[132] = (float(*)[132])smem;
        int rbk = bid - 6144;
        int seg = rbk >> 8;
        {
            int hl = tid >> 1, ep = (tid & 1) * 4;
            float4 v = *(const float4*)(rw + (size_t)(seg * kSeg + hl) * kE + ep);
            rwT[ep + 0][hl] = v.x; rwT[ep + 1][hl] = v.y;
            rwT[ep + 2][hl] = v.z; rwT[ep + 3][hl] = v.w;
        }
        __syncthreads();
        int wave = (rbk & 255) * 4 + (tid >> 6);
        int lane = tid & 63;
        int tg = lane >> 3, e = lane & 7;
        int t = wave * 8 + tg;
        const float* xp = x + (size_t)t * kH + seg * kSeg;
        float a0 = 0.f, a1 = 0.f;
#pragma unroll 4
        for (int i = 0; i < kSeg / 8; ++i) {
            float4 xv0 = *(const float4*)(xp + i * 8);
            float4 xv1 = *(const float4*)(xp + i * 8 + 4);
            float4 wv0 = *(const float4*)&rwT[e][i * 8];
            float4 wv1 = *(const float4*)&rwT[e][i * 8 + 4];
            a0 += xv0.x * wv0.x + xv0.y * wv0.y + xv0.z * wv0.z + xv0.w * wv0.w;
            a1 += xv1.x * wv1.x + xv1.y * wv1.y + xv1.z * wv1.z + xv1.w * wv1.w;
        }
        plog[(size_t)t * 64 + e * 8 + seg] = a0 + a1;
    }
}

// ---------------- K2: router finalize (softmax/argmax/gate) + perm2 + last-block scan --
// Rank assignment: block-local LDS histogram, then ONE global atomic per (block,
// expert) onto 128B-padded counters. perm2[e][rank] = token built directly — no
// aoff/gather pass needed downstream.
__global__ __launch_bounds__(256) void k_router_final(const float* __restrict__ plog,
                                                      const float* __restrict__ rb,
                                                      float* __restrict__ gate,
                                                      int* __restrict__ perm2,
                                                      int* __restrict__ cnt,
                                                      int* __restrict__ done,
                                                      int* __restrict__ tile_e,
                                                      int* __restrict__ tile_row) {
    __shared__ int lcnt[kE];
    __shared__ int lbase[kE];
    int tid = threadIdx.x;
    if (tid < kE) lcnt[tid] = 0;
    __syncthreads();

    int wave = blockIdx.x * 4 + (tid >> 6);
    int lane = tid & 63;
    int tg = lane >> 3, e = lane & 7;
    int t = wave * 8 + tg;
    const float* pp = plog + (size_t)t * 64 + e * 8;
    float4 p0 = *(const float4*)pp;
    float4 p1 = *(const float4*)(pp + 4);
    float acc = rb[e] + ((p0.x + p0.y) + (p0.z + p0.w)) + ((p1.x + p1.y) + (p1.z + p1.w));
    // argmax over the 8 expert lanes (first-max tie-break like np.argmax)
    float m = acc; int bi = e;
#pragma unroll
    for (int s = 1; s < 8; s <<= 1) {
        float om = __shfl_xor(m, s);
        int   ob = __shfl_xor(bi, s);
        if (om > m || (om == m && ob < bi)) { m = om; bi = ob; }
    }
    float p = __expf(acc - m);
    float sum = p;
#pragma unroll
    for (int s = 1; s < 8; s <<= 1) sum += __shfl_xor(sum, s);

    int lrank = 0;
    if (e == 0) {
        gate[t] = 1.0f / sum;                       // softmax prob at argmax
        lrank = atomicAdd(&lcnt[bi], 1);            // LDS atomic: local rank
    }
    __syncthreads();
    if (tid < kE) lbase[tid] = atomicAdd(&cnt[tid * kCntStride], lcnt[tid]);
    __syncthreads();
    if (e == 0) perm2[bi * kT + lbase[bi] + lrank] = t;   // sorted row -> token

    // ---- last block to finish builds the m-tile table (expert-LOCAL rows) ----
    __syncthreads();
    if (tid == 0) {
        __threadfence();
        int old = atomicAdd(done, 1);
        if (old == (int)gridDim.x - 1) {
            __threadfence();
            int tt = 0;
            for (int ee = 0; ee < kE; ++ee) {
                int c = atomicAdd(&cnt[ee * kCntStride], 0);   // device-coherent read
                int nt = (c + 127) >> 7;
                for (int i = 0; i < nt; ++i) { tile_e[tt] = ee; tile_row[tt] = i << 7; ++tt; }
            }
            for (; tt < kMaxTiles; ++tt) tile_e[tt] = -1;
        }
    }
}

// ---------------- K3: grouped GEMM, 128x128 tile, BK=64, mfma_f32_16x16x32_bf16 --------
// A-tiles are gathered ON THE FLY from xb via perm2 (per-lane global addresses into
// global_load_lds; LDS dest stays uniform-base+lane*16). Pad rows (>= cnt[e]) read
// token 0 and are skipped in the epilogue — no zero-fill pass, no gathered A array.
// Staging rows are 128 B (8 x 16B chunks) with chunk-XOR swizzle on the GLOBAL side
// (LDS[r][s] = G[r][s^(r&7)]); fragment reads un-swizzle with sw = (g^(l15&7)).
constexpr int kBK = 64;

__global__ __launch_bounds__(256, 2) void k_gemm(const unsigned short* __restrict__ xb,
                                                 const unsigned short* __restrict__ Wt,
                                                 const float* __restrict__ eb,
                                                 const int* __restrict__ perm2,
                                                 const float* __restrict__ gate,
                                                 const int* __restrict__ cnt,
                                                 const int* __restrict__ tile_e,
                                                 const int* __restrict__ tile_row,
                                                 float* __restrict__ out) {
    int bm = blockIdx.x, bn = blockIdx.y;
    int e = tile_e[bm];
    if (e < 0) return;
    int l0 = tile_row[bm];                       // expert-local row base
    int ce = cnt[e * kCntStride];
    const int* pe = perm2 + e * kT;

    __shared__ __align__(16) unsigned short As[128 * kBK];   // 16 KB
    __shared__ __align__(16) unsigned short Bs[128 * kBK];   // 16 KB

    int tid = threadIdx.x;
    int wave = tid >> 6, lane = tid & 63;
    int wm = wave & 1, wn = wave >> 1;           // 2x2 waves over 128x128
    int quad = lane >> 4, l15 = lane & 15;

    floatx4 acc[4][4];
#pragma unroll
    for (int i = 0; i < 4; ++i)
#pragma unroll
        for (int j = 0; j < 4; ++j) acc[i][j] = floatx4{0.f, 0.f, 0.f, 0.f};

    // staging: wave stages rows [wave*32, wave*32+32), 4 issues of 8 rows each.
    int lrow8 = lane >> 3;                       // 0..7
    int lseg8 = (lane & 7) ^ lrow8;              // swizzled 16B chunk (global side)
    const unsigned short* aPj[4];
#pragma unroll
    for (int j = 0; j < 4; ++j) {
        int lr = l0 + wave * 32 + j * 8 + lrow8;
        int tok = (lr < ce) ? pe[lr] : 0;        // pad rows read token 0, skipped later
        aPj[j] = xb + (size_t)tok * kH + lseg8 * 8;
    }
    const unsigned short* bP = Wt + ((size_t)e << 20)
                             + (size_t)(bn * 128 + wave * 32 + lrow8) * kH + lseg8 * 8;
    unsigned short* lA = &As[(wave * 32) * kBK];
    unsigned short* lB = &Bs[(wave * 32) * kBK];

    // fragment read chunk: global seg g = ks*4+quad at row l15 -> LDS seg g^(l15&7)
    int sw0 = ((0 * 4 + quad) ^ (l15 & 7)) * 8;
    int sw1 = ((1 * 4 + quad) ^ (l15 & 7)) * 8;

    for (int k0 = 0; k0 < kH; k0 += kBK) {
        __syncthreads();                         // prior iter's fragment reads complete
#pragma unroll
        for (int j = 0; j < 4; ++j) {
            GLDS16(aPj[j] + k0, lA + j * 8 * kBK);
            GLDS16(bP + (size_t)(j * 8) * kH + k0, lB + j * 8 * kBK);
        }
        __syncthreads();                         // drains vmcnt -> tile visible

        short8 af[4][2], bf[4][2];
#pragma unroll
        for (int i = 0; i < 4; ++i) {
            int r = (wm * 64 + i * 16 + l15) * kBK;
            af[i][0] = *(const short8*)&As[r + sw0];
            af[i][1] = *(const short8*)&As[r + sw1];
        }
#pragma unroll
        for (int i = 0; i < 4; ++i) {
            int r = (wn * 64 + i * 16 + l15) * kBK;
            bf[i][0] = *(const short8*)&Bs[r + sw0];
            bf[i][1] = *(const short8*)&Bs[r + sw1];
        }
#pragma unroll
        for (int ks = 0; ks < 2; ++ks)
#pragma unroll
            for (int i = 0; i < 4; ++i)
#pragma unroll
                for (int j = 0; j < 4; ++j)
                    acc[i][j] = __builtin_amdgcn_mfma_f32_16x16x32_bf16(af[i][ks], bf[j][ks],
                                                                        acc[i][j], 0, 0, 0);
    }

    // epilogue: C row = quad*4 + reg, col = lane&15 (verified m89/m91 mapping)
    int colbase = bn * 128 + wn * 64;
#pragma unroll
    for (int i = 0; i < 4; ++i) {
        int rl = l0 + wm * 64 + i * 16 + quad * 4;
#pragma unroll
        for (int rg = 0; rg < 4; ++rg) {
            int lr = rl + rg;
            if (lr >= ce) continue;         // pad row
            int tok = pe[lr];
            float g = gate[tok];
            float* op = out + (size_t)tok * kH;
#pragma unroll
            for (int j = 0; j < 4; ++j) {
                int col = colbase + j * 16 + l15;
                op[col] = g * (acc[i][j][rg] + eb[e * kH + col]);
            }
        }
    }
}

extern "C" void kernel_launch(void* const* d_in, const int* in_sizes, int n_in,
                              void* d_out, int out_size, void* d_ws, size_t ws_size,
                              hipStream_t stream) {
    const float* x  = (const float*)d_in[0];   // [T,H]
    const float* rw = (const float*)d_in[1];   // [H,E]
    const float* rb = (const float*)d_in[2];   // [E]
    const float* ew = (const float*)d_in[3];   // [E,H,H]
    const float* eb = (const float*)d_in[4];   // [E,H]
    float* out = (float*)d_out;                // [T,H]

    char* p = (char*)d_ws;
    unsigned short* Wt = (unsigned short*)p; p += (size_t)kE * kH * kH * 2;   // 16 MB
    unsigned short* xb = (unsigned short*)p; p += (size_t)kT * kH * 2;        // 16 MB
    float* plog  = (float*)p; p += (size_t)kT * 64 * 4;                       // 2 MB
    float* gate  = (float*)p; p += (size_t)kT * 4;
    int* perm2   = (int*)p;   p += (size_t)kE * kT * 4;                       // 256 KB
    int* cnt     = (int*)p;   p += kE * kCntStride * 4;   // 128B-padded counters
    int* done    = (int*)p;   p += 64;
    int* tile_e  = (int*)p;   p += kMaxTiles * 4;
    int* tile_r  = (int*)p;   p += kMaxTiles * 4;

    k_prep<<<8192, 256, 0, stream>>>(ew, Wt, x, xb, rw, plog, cnt, done);
    k_router_final<<<kT / 32, 256, 0, stream>>>(plog, rb, gate, perm2, cnt, done,
                                                tile_e, tile_r);
    dim3 gg(kMaxTiles, kH / 128);
    k_gemm<<<gg, 256, 0, stream>>>(xb, Wt, eb, perm2, gate, cnt, tile_e, tile_r, out);
}